// Round 17
// baseline (930.206 us; speedup 1.0000x reference)
//
#include <hip/hip_runtime.h>
#include <hip/hip_bf16.h>

constexpr int B    = 16;
constexpr int N    = 4096;
constexpr int CIN  = 64;
constexpr int COUT = 128;
constexpr int M    = 1024;
constexpr int K    = 32;

constexpr int K1  = 96;   // layer-1 MFMA K: 64 x + 3 rel + 29 zero pad
constexpr int LDH = 136;  // A2 row stride (pad +8)

typedef __attribute__((ext_vector_type(8))) short short8;
typedef __attribute__((ext_vector_type(4))) short short4v;
typedef __attribute__((ext_vector_type(4))) float f32x4;
typedef __attribute__((ext_vector_type(2))) float f32x2;

// RNE float->bf16 (finite values)
static __device__ __forceinline__ unsigned short f2bf(float f) {
  unsigned u = __float_as_uint(f);
  unsigned r = (u + 0x7FFFu + ((u >> 16) & 1u)) >> 16;
  return (unsigned short)r;
}

// fast mish: v * tanh(softplus(v)) == v * s/(s+2), s = u^2+2u, u = e^v
static __device__ __forceinline__ float fast_mish(float v) {
  float u = __expf(v);
  float s = u * (u + 2.0f);
  float den = s + 2.0f;
  float r;
  asm("v_rcp_f32 %0, %1" : "=v"(r) : "v"(den));
  float t = s * r;
  return (v > 60.f) ? v : v * t;
}

static __device__ __forceinline__ f32x2 fmin2(f32x2 a, f32x2 b) {
  f32x2 r;
  r.x = fminf(a.x, b.x);
  r.y = fminf(a.y, b.y);
  return r;
}

// ---------------------------------------------------------------------------
// Wave-wide u32 max via DPP (row_shr 1/2/4/8, row_bcast 15/31, readlane 63).
// ---------------------------------------------------------------------------
template <int CTRL, int RM>
static __device__ __forceinline__ unsigned dpp_umax_step(unsigned x) {
  int o = __builtin_amdgcn_update_dpp((int)x, (int)x, CTRL, RM, 0xF, false);
  unsigned u = (unsigned)o;
  return x > u ? x : u;
}
static __device__ __forceinline__ unsigned wave_umax(unsigned x) {
  x = dpp_umax_step<0x111, 0xF>(x);  // row_shr:1
  x = dpp_umax_step<0x112, 0xF>(x);  // row_shr:2
  x = dpp_umax_step<0x114, 0xF>(x);  // row_shr:4
  x = dpp_umax_step<0x118, 0xF>(x);  // row_shr:8
  x = dpp_umax_step<0x142, 0xA>(x);  // row_bcast:15 -> rows 1,3
  x = dpp_umax_step<0x143, 0xC>(x);  // row_bcast:31 -> rows 2,3
  return (unsigned)__builtin_amdgcn_readlane((int)x, 63);
}

static __device__ __forceinline__ unsigned long long umax64(unsigned long long a,
                                                            unsigned long long b) {
  return a > b ? a : b;
}

// ---------------------------------------------------------------------------
// FPS v11 = fps10 with ZERO global stores in the serial loop. Per iteration,
// tid0's 4 global stores (idx+pout) forced a `s_waitcnt vmcnt(0)` before the
// barrier -> wave0 waited ~150-300cyc for store acks every iter, delaying all
// 8 waves. Now: winner index -> LDS ring (ds_write, lgkm-drained ~30cyc);
// idx_out/pout written once, coalesced, in an epilogue (q gathered from sp).
// Selection math bit-identical to fps10. Tail blocks do weight prep.
// ---------------------------------------------------------------------------
__global__ __launch_bounds__(512) void fps11_kernel(const float* __restrict__ pos,
                                                    int* __restrict__ idx_out,
                                                    float* __restrict__ pout,
                                                    float* __restrict__ pos4,
                                                    const float* __restrict__ W1,
                                                    const float* __restrict__ W2,
                                                    unsigned short* __restrict__ W1t,
                                                    unsigned short* __restrict__ W2t) {
#pragma clang fp contract(off)
  if (blockIdx.x >= B) {  // ---- weight-prep tail blocks ----
    const int n = blockIdx.x - B;  // 0..127
    const int t = threadIdx.x;
    if (t < K1) {
      W1t[n * K1 + t] = (t < 67) ? f2bf(W1[t * 128 + n]) : (unsigned short)0;
    } else if (t < K1 + 128) {
      const int k = t - K1;
      W2t[n * 128 + k] = f2bf(W2[k * 128 + n]);
    }
    return;
  }
  const int b   = blockIdx.x;
  const int tid = threadIdx.x;
  __shared__ float sp[N][4];
  __shared__ unsigned long long skey[2][8];
  __shared__ int sidx[M];
  const float* p = pos + (size_t)b * (N * 3);
  float* p4 = pos4 + (size_t)b * N * 4;

  f32x2 px2[4], py2[4], pz2[4], mind2[4];
#pragma unroll
  for (int j = 0; j < 8; j++) {
    const int n = tid + j * 512;
    const float x = p[3 * n + 0];
    const float y = p[3 * n + 1];
    const float z = p[3 * n + 2];
    px2[j >> 1][j & 1] = x;
    py2[j >> 1][j & 1] = y;
    pz2[j >> 1][j & 1] = z;
    mind2[j >> 1][j & 1] = __builtin_inff();
    f32x4 v;
    v[0] = x; v[1] = y; v[2] = z; v[3] = 0.f;
    *(f32x4*)(&sp[n][0]) = v;
    *(f32x4*)(p4 + 4 * n) = v;  // prologue dump; drained at first barrier
  }
  float qx = p[0], qy = p[1], qz = p[2];
  if (tid == 0) sidx[0] = 0;
  __syncthreads();

  const int wv = tid >> 6, lane = tid & 63;
  for (int t = 1; t < M; t++) {
    const f32x2 nqx = {-qx, -qx};
    const f32x2 nqy = {-qy, -qy};
    const f32x2 nqz = {-qz, -qz};
#pragma unroll
    for (int k = 0; k < 4; k++) {
      f32x2 dx = px2[k] + nqx;                    // v_pk_add_f32 (exact sub)
      f32x2 dy = py2[k] + nqy;
      f32x2 dz = pz2[k] + nqz;
      f32x2 s = (dx * dx + dy * dy) + dz * dz;    // numpy order, no fma
      mind2[k] = fmin2(mind2[k], s);
    }
    // post-loop per-lane argmax; ties -> smallest j (descending eq-scan)
    const float m01 = fmaxf(fmaxf(mind2[0].x, mind2[0].y),
                            fmaxf(mind2[1].x, mind2[1].y));
    const float m23 = fmaxf(fmaxf(mind2[2].x, mind2[2].y),
                            fmaxf(mind2[3].x, mind2[3].y));
    const float bv = fmaxf(m01, m23);
    unsigned bn = (unsigned)(tid + 7 * 512);
    bn = (mind2[3].x == bv) ? (unsigned)(tid + 6 * 512) : bn;
    bn = (mind2[2].y == bv) ? (unsigned)(tid + 5 * 512) : bn;
    bn = (mind2[2].x == bv) ? (unsigned)(tid + 4 * 512) : bn;
    bn = (mind2[1].y == bv) ? (unsigned)(tid + 3 * 512) : bn;
    bn = (mind2[1].x == bv) ? (unsigned)(tid + 2 * 512) : bn;
    bn = (mind2[0].y == bv) ? (unsigned)(tid + 1 * 512) : bn;
    bn = (mind2[0].x == bv) ? (unsigned)tid : bn;

    const unsigned vb = __float_as_uint(bv);  // nonneg floats: monotone bits
    const unsigned wb = wave_umax(vb);        // wave max value
    unsigned tk = (vb == wb) ? ~bn : 0u;
    tk = wave_umax(tk);                       // ties -> smallest n
    const int par = t & 1;
    if (lane == 0) skey[par][wv] = ((unsigned long long)wb << 32) | tk;
    __syncthreads();
    const unsigned long long k0 = skey[par][0];
    const unsigned long long k1 = skey[par][1];
    const unsigned long long k2 = skey[par][2];
    const unsigned long long k3 = skey[par][3];
    const unsigned long long k4 = skey[par][4];
    const unsigned long long k5 = skey[par][5];
    const unsigned long long k6 = skey[par][6];
    const unsigned long long k7 = skey[par][7];
    const unsigned long long bb =
        umax64(umax64(umax64(k0, k1), umax64(k2, k3)),
               umax64(umax64(k4, k5), umax64(k6, k7)));
    const unsigned n = ~(unsigned)bb;
    const f32x4 qv = *(const f32x4*)(&sp[n][0]);  // one dependent b128 read
    qx = qv[0];
    qy = qv[1];
    qz = qv[2];
    if (tid == 0) sidx[t] = (int)n;  // LDS only — no vmcnt drain at barrier
  }
  __syncthreads();
  // epilogue: bulk, coalesced global writes (once per kernel, off the chain)
  for (int i = tid; i < M; i += 512) {
    const int n = sidx[i];
    idx_out[b * M + i] = n;
    const f32x4 v = *(const f32x4*)(&sp[n][0]);
    pout[(size_t)(b * M + i) * 3 + 0] = v[0];
    pout[(size_t)(b * M + i) * 3 + 1] = v[1];
    pout[(size_t)(b * M + i) * 3 + 2] = v[2];
  }
}

// ---------------------------------------------------------------------------
// Fused KNN+MLP v8 (unchanged from round 16): 512 threads = 8 waves = 8
// same-cloud centroids/block. Phase 1: LDS-staged KNN, winners -> n0/n1
// registers. Barrier. Phase 2: wave-private A2 MFMA MLP, zero barriers.
// ---------------------------------------------------------------------------
__global__ __launch_bounds__(512) void knnmlp8_kernel(
    const float* __restrict__ x, const float* __restrict__ pos4,
    const unsigned short* __restrict__ W1t, const unsigned short* __restrict__ W2t,
    const float* __restrict__ b1, const float* __restrict__ b2,
    const float* __restrict__ Wlin, const float* __restrict__ blin,
    const int* __restrict__ idx, float* __restrict__ xout) {
  __shared__ __align__(16) unsigned char smem[8 * 32 * LDH * 2];  // 69632 B
  const int tid  = threadIdx.x;
  const int wv   = tid >> 6;
  const int lane = tid & 63;
  const int lrow = lane & 15;
  const int g    = lane >> 4;
  const int cent = blockIdx.x * 8 + wv;   // 8 cents share one cloud
  const int b    = cent >> 10;
  const float* p4 = pos4 + (size_t)b * N * 4;

  float* sp4 = (float*)smem;  // phase-1 view: 64 KB point stage
  for (int i = tid; i < N; i += 512) {
    *(f32x4*)(sp4 + 4 * i) = *(const f32x4*)(p4 + 4 * i);
  }
  __syncthreads();

  const int sel = idx[cent];
  const f32x4 q = *(const f32x4*)(sp4 + 4 * sel);
  const float qx = q[0], qy = q[1], qz = q[2];
  int n0 = 0, n1 = 0;
  {
#pragma clang fp contract(off)
    const f32x2 nqx = {-qx, -qx};
    const f32x2 nqy = {-qy, -qy};
    const f32x2 nqz = {-qz, -qz};
    float d[64];
#pragma unroll
    for (int jj = 0; jj < 32; jj++) {
      const f32x4 v0 = *(const f32x4*)(sp4 + 4 * ((2 * jj + 0) * 64 + lane));
      const f32x4 v1 = *(const f32x4*)(sp4 + 4 * ((2 * jj + 1) * 64 + lane));
      f32x2 vx = {v0[0], v1[0]};
      f32x2 vy = {v0[1], v1[1]};
      f32x2 vz = {v0[2], v1[2]};
      f32x2 dx = vx + nqx;
      f32x2 dy = vy + nqy;
      f32x2 dz = vz + nqz;
      f32x2 s = (dx * dx + dy * dy) + dz * dz;  // numpy order, exact
      d[2 * jj + 0] = s.x;
      d[2 * jj + 1] = s.y;
    }
    float gv[8];
    int gj[8];
#pragma unroll
    for (int gg = 0; gg < 8; gg++) {
      gv[gg] = __builtin_inff();
      gj[gg] = 8 * gg;
#pragma unroll
      for (int e = 0; e < 8; e++) {
        const int j = 8 * gg + e;
        bool c = d[j] < gv[gg];  // strict: ascending j keeps smallest on ties
        gv[gg] = c ? d[j] : gv[gg];
        gj[gg] = c ? j : gj[gg];
      }
    }
    for (int r = 0; r < K; r++) {
      float bv = __builtin_inff();
      int bj = 0;
#pragma unroll
      for (int gg = 0; gg < 8; gg++) {
        bool c = gv[gg] < bv;
        bv = c ? gv[gg] : bv;
        bj = c ? gj[gg] : bj;
      }
      const unsigned bn = (unsigned)(bj * 64 + lane);
      const unsigned nb = ~__float_as_uint(bv);  // ~bits: umax -> min dist
      const unsigned wnb = wave_umax(nb);
      unsigned tk = (nb == wnb) ? (0xFFFFFFFFu - bn) : 0u;
      tk = wave_umax(tk);                        // ties -> smallest global n
      const unsigned wn = 0xFFFFFFFFu - tk;      // uniform across wave
      n0 = (r == lrow) ? (int)wn : n0;           // capture for MLP
      n1 = (r == 16 + lrow) ? (int)wn : n1;
      const int wj = (int)(wn >> 6);
      const int wl = (int)(wn & 63);
      const int wg = wj >> 3;
#pragma unroll
      for (int gg = 0; gg < 8; gg++) {
        if (gg == wg) {  // scalar-uniform: only winner's group pays
#pragma unroll
          for (int e = 0; e < 8; e++) {
            if (8 * gg + e == wj) {
              if (lane == wl) d[8 * gg + e] = __builtin_inff();
            }
          }
          float nv = __builtin_inff();
          int nj = 8 * gg;
#pragma unroll
          for (int e = 0; e < 8; e++) {
            const int j = 8 * gg + e;
            bool c = d[j] < nv;
            nv = c ? d[j] : nv;
            nj = c ? j : nj;
          }
          gv[gg] = nv;
          gj[gg] = nj;
        }
      }
    }
  }
  __syncthreads();  // all waves done reading sp4 -> LDS reusable as A2

  // ================== phase 2: MLP (wave-private A2 slice) ==================
  unsigned short* A2 = (unsigned short*)smem + wv * (32 * LDH);

  short8 a0[3], a1[3];
  {
    const float* xr0 = x + ((size_t)b * N + n0) * CIN;
    const float* xr1 = x + ((size_t)b * N + n1) * CIN;
#pragma unroll
    for (int kc = 0; kc < 2; kc++) {
      const int k0 = kc * 32 + g * 8;
      f32x4 u0 = *(const f32x4*)(xr0 + k0);
      f32x4 u1 = *(const f32x4*)(xr0 + k0 + 4);
      f32x4 v0 = *(const f32x4*)(xr1 + k0);
      f32x4 v1 = *(const f32x4*)(xr1 + k0 + 4);
      short8 ha, hb;
#pragma unroll
      for (int e = 0; e < 4; e++) {
        ha[e] = (short)f2bf(u0[e]);
        ha[e + 4] = (short)f2bf(u1[e]);
        hb[e] = (short)f2bf(v0[e]);
        hb[e + 4] = (short)f2bf(v1[e]);
      }
      a0[kc] = ha;
      a1[kc] = hb;
    }
    short8 z = {};
    a0[2] = z;
    a1[2] = z;
    if (g == 0) {  // k = 64..71: {rel.x, rel.y, rel.z, 0...}
      float r0x = p4[4 * n0 + 0] - qx, r0y = p4[4 * n0 + 1] - qy, r0z = p4[4 * n0 + 2] - qz;
      float r1x = p4[4 * n1 + 0] - qx, r1y = p4[4 * n1 + 1] - qy, r1z = p4[4 * n1 + 2] - qz;
      a0[2][0] = (short)f2bf(r0x); a0[2][1] = (short)f2bf(r0y); a0[2][2] = (short)f2bf(r0z);
      a1[2][0] = (short)f2bf(r1x); a1[2][1] = (short)f2bf(r1y); a1[2][2] = (short)f2bf(r1z);
    }
  }

  // layer 1 (swapped): lane holds 4 k-consecutive channels -> packed b64
#pragma unroll 2
  for (int nt = 0; nt < 8; nt++) {
    const unsigned short* w1r = W1t + (size_t)(nt * 16 + lrow) * K1 + g * 8;
    f32x4 c0 = {}, c1 = {};
#pragma unroll
    for (int kc = 0; kc < 3; kc++) {
      short8 afr = *(const short8*)(w1r + kc * 32);
      c0 = __builtin_amdgcn_mfma_f32_16x16x32_bf16(afr, a0[kc], c0, 0, 0, 0);
      c1 = __builtin_amdgcn_mfma_f32_16x16x32_bf16(afr, a1[kc], c1, 0, 0, 0);
    }
    const int kbase = nt * 16 + g * 4;
    const f32x4 bb = *(const f32x4*)(b1 + kbase);
    short4v h0, h1;
#pragma unroll
    for (int reg = 0; reg < 4; reg++) {
      h0[reg] = (short)f2bf(fast_mish(c0[reg] + bb[reg]));
      h1[reg] = (short)f2bf(fast_mish(c1[reg] + bb[reg]));
    }
    *(short4v*)(A2 + lrow * LDH + kbase) = h0;
    *(short4v*)(A2 + (16 + lrow) * LDH + kbase) = h1;
  }

  f32x4 xq[4];
  {
    const float* xs = x + ((size_t)b * N + sel) * CIN + g * 16;
#pragma unroll
    for (int v = 0; v < 4; v++) xq[v] = *(const f32x4*)(xs + 4 * v);
  }

  // layer 2 + max over 32 rows + epilogue (in-wave LDS ordering)
#pragma unroll 2
  for (int nt = 0; nt < 8; nt++) {
    const unsigned short* w2r = W2t + (size_t)(nt * 16 + lrow) * 128 + g * 8;
    f32x4 c0 = {}, c1 = {};
#pragma unroll
    for (int kc = 0; kc < 4; kc++) {
      short8 af0 = *(const short8*)(A2 + lrow * LDH + kc * 32 + g * 8);
      short8 af1 = *(const short8*)(A2 + (16 + lrow) * LDH + kc * 32 + g * 8);
      short8 bfr = *(const short8*)(w2r + kc * 32);
      c0 = __builtin_amdgcn_mfma_f32_16x16x32_bf16(af0, bfr, c0, 0, 0, 0);
      c1 = __builtin_amdgcn_mfma_f32_16x16x32_bf16(af1, bfr, c1, 0, 0, 0);
    }
    float pm = fmaxf(fmaxf(fmaxf(c0[0], c0[1]), fmaxf(c0[2], c0[3])),
                     fmaxf(fmaxf(c1[0], c1[1]), fmaxf(c1[2], c1[3])));
    pm = fmaxf(pm, __shfl_xor(pm, 16, 64));
    pm = fmaxf(pm, __shfl_xor(pm, 32, 64));  // max over all 32 rows, col j
    const int j = nt * 16 + lrow;
    float s = 0.f;
#pragma unroll
    for (int e = 0; e < 16; e++) {
      s += xq[e >> 2][e & 3] * Wlin[(g * 16 + e) * 128 + j];
    }
    s += __shfl_xor(s, 16, 64);
    s += __shfl_xor(s, 32, 64);  // full 64-k dot
    if (g == 0) {
      xout[(size_t)cent * 128 + j] = pm + b2[j] + s + blin[j];
    }
  }
}

// ---------------------------------------------------------------------------
extern "C" void kernel_launch(void* const* d_in, const int* in_sizes, int n_in,
                              void* d_out, int out_size, void* d_ws, size_t ws_size,
                              hipStream_t stream) {
  const float* x    = (const float*)d_in[0];
  const float* pos  = (const float*)d_in[1];
  const float* W1   = (const float*)d_in[2];
  const float* b1   = (const float*)d_in[3];
  const float* W2   = (const float*)d_in[4];
  const float* b2   = (const float*)d_in[5];
  const float* Wlin = (const float*)d_in[6];
  const float* blin = (const float*)d_in[7];

  float* out  = (float*)d_out;                 // float32 outputs
  float* xout = out;                           // [B*M*COUT]
  float* pout = out + (size_t)B * M * COUT;    // [B*M*3]

  char* ws = (char*)d_ws;
  int* idx            = (int*)ws;                           // 64 KB
  unsigned short* W1t = (unsigned short*)(ws + 65536);      // 24 KB
  unsigned short* W2t = (unsigned short*)(ws + 90112);      // 32 KB
  float* pos4         = (float*)(ws + 122880);              // 1 MB

  fps11_kernel<<<dim3(B + 128), dim3(512), 0, stream>>>(pos, idx, pout, pos4,
                                                        W1, W2, W1t, W2t);
  knnmlp8_kernel<<<dim3(B * M / 8), dim3(512), 0, stream>>>(
      x, pos4, W1t, W2t, b1, b2, Wlin, blin, idx, xout);
}

// Round 18
// 897.275 us; speedup vs baseline: 1.0367x; 1.0367x over previous
//
#include <hip/hip_runtime.h>
#include <hip/hip_bf16.h>

constexpr int B    = 16;
constexpr int N    = 4096;
constexpr int CIN  = 64;
constexpr int COUT = 128;
constexpr int M    = 1024;
constexpr int K    = 32;

constexpr int K1  = 96;   // layer-1 MFMA K: 64 x + 3 rel + 29 zero pad
constexpr int LDH = 136;  // A2 row stride (pad +8)

typedef __attribute__((ext_vector_type(8))) short short8;
typedef __attribute__((ext_vector_type(4))) short short4v;
typedef __attribute__((ext_vector_type(4))) float f32x4;
typedef __attribute__((ext_vector_type(2))) float f32x2;

// RNE float->bf16 (finite values)
static __device__ __forceinline__ unsigned short f2bf(float f) {
  unsigned u = __float_as_uint(f);
  unsigned r = (u + 0x7FFFu + ((u >> 16) & 1u)) >> 16;
  return (unsigned short)r;
}

// fast mish: v * tanh(softplus(v)) == v * s/(s+2), s = u^2+2u, u = e^v
static __device__ __forceinline__ float fast_mish(float v) {
  float u = __expf(v);
  float s = u * (u + 2.0f);
  float den = s + 2.0f;
  float r;
  asm("v_rcp_f32 %0, %1" : "=v"(r) : "v"(den));
  float t = s * r;
  return (v > 60.f) ? v : v * t;
}

static __device__ __forceinline__ f32x2 fmin2(f32x2 a, f32x2 b) {
  f32x2 r;
  r.x = fminf(a.x, b.x);
  r.y = fminf(a.y, b.y);
  return r;
}

// ---------------------------------------------------------------------------
// Wave-wide u32 max via DPP (row_shr 1/2/4/8, row_bcast 15/31, readlane 63).
// ---------------------------------------------------------------------------
template <int CTRL, int RM>
static __device__ __forceinline__ unsigned dpp_umax_step(unsigned x) {
  int o = __builtin_amdgcn_update_dpp((int)x, (int)x, CTRL, RM, 0xF, false);
  unsigned u = (unsigned)o;
  return x > u ? x : u;
}
static __device__ __forceinline__ unsigned wave_umax(unsigned x) {
  x = dpp_umax_step<0x111, 0xF>(x);  // row_shr:1
  x = dpp_umax_step<0x112, 0xF>(x);  // row_shr:2
  x = dpp_umax_step<0x114, 0xF>(x);  // row_shr:4
  x = dpp_umax_step<0x118, 0xF>(x);  // row_shr:8
  x = dpp_umax_step<0x142, 0xA>(x);  // row_bcast:15 -> rows 1,3
  x = dpp_umax_step<0x143, 0xC>(x);  // row_bcast:31 -> rows 2,3
  return (unsigned)__builtin_amdgcn_readlane((int)x, 63);
}

static __device__ __forceinline__ unsigned long long umax64(unsigned long long a,
                                                            unsigned long long b) {
  return a > b ? a : b;
}

// ---------------------------------------------------------------------------
// FPS v11 (measured floor of this structure: ~640us): 512 thr / 8 waves,
// points in registers as f32x2 pairs (packed-FP32 dist, IEEE-exact), argmax
// hoisted out of dist loop, winner index to LDS ring, bulk epilogue writes.
// Tail blocks do the W1/W2 transpose prep on otherwise-idle CUs.
// ---------------------------------------------------------------------------
__global__ __launch_bounds__(512) void fps11_kernel(const float* __restrict__ pos,
                                                    int* __restrict__ idx_out,
                                                    float* __restrict__ pout,
                                                    float* __restrict__ pos4,
                                                    const float* __restrict__ W1,
                                                    const float* __restrict__ W2,
                                                    unsigned short* __restrict__ W1t,
                                                    unsigned short* __restrict__ W2t) {
#pragma clang fp contract(off)
  if (blockIdx.x >= B) {  // ---- weight-prep tail blocks ----
    const int n = blockIdx.x - B;  // 0..127
    const int t = threadIdx.x;
    if (t < K1) {
      W1t[n * K1 + t] = (t < 67) ? f2bf(W1[t * 128 + n]) : (unsigned short)0;
    } else if (t < K1 + 128) {
      const int k = t - K1;
      W2t[n * 128 + k] = f2bf(W2[k * 128 + n]);
    }
    return;
  }
  const int b   = blockIdx.x;
  const int tid = threadIdx.x;
  __shared__ float sp[N][4];
  __shared__ unsigned long long skey[2][8];
  __shared__ int sidx[M];
  const float* p = pos + (size_t)b * (N * 3);
  float* p4 = pos4 + (size_t)b * N * 4;

  f32x2 px2[4], py2[4], pz2[4], mind2[4];
#pragma unroll
  for (int j = 0; j < 8; j++) {
    const int n = tid + j * 512;
    const float x = p[3 * n + 0];
    const float y = p[3 * n + 1];
    const float z = p[3 * n + 2];
    px2[j >> 1][j & 1] = x;
    py2[j >> 1][j & 1] = y;
    pz2[j >> 1][j & 1] = z;
    mind2[j >> 1][j & 1] = __builtin_inff();
    f32x4 v;
    v[0] = x; v[1] = y; v[2] = z; v[3] = 0.f;
    *(f32x4*)(&sp[n][0]) = v;
    *(f32x4*)(p4 + 4 * n) = v;  // prologue dump; drained at first barrier
  }
  float qx = p[0], qy = p[1], qz = p[2];
  if (tid == 0) sidx[0] = 0;
  __syncthreads();

  const int wv = tid >> 6, lane = tid & 63;
  for (int t = 1; t < M; t++) {
    const f32x2 nqx = {-qx, -qx};
    const f32x2 nqy = {-qy, -qy};
    const f32x2 nqz = {-qz, -qz};
#pragma unroll
    for (int k = 0; k < 4; k++) {
      f32x2 dx = px2[k] + nqx;                    // v_pk_add_f32 (exact sub)
      f32x2 dy = py2[k] + nqy;
      f32x2 dz = pz2[k] + nqz;
      f32x2 s = (dx * dx + dy * dy) + dz * dz;    // numpy order, no fma
      mind2[k] = fmin2(mind2[k], s);
    }
    // post-loop per-lane argmax; ties -> smallest j (descending eq-scan)
    const float m01 = fmaxf(fmaxf(mind2[0].x, mind2[0].y),
                            fmaxf(mind2[1].x, mind2[1].y));
    const float m23 = fmaxf(fmaxf(mind2[2].x, mind2[2].y),
                            fmaxf(mind2[3].x, mind2[3].y));
    const float bv = fmaxf(m01, m23);
    unsigned bn = (unsigned)(tid + 7 * 512);
    bn = (mind2[3].x == bv) ? (unsigned)(tid + 6 * 512) : bn;
    bn = (mind2[2].y == bv) ? (unsigned)(tid + 5 * 512) : bn;
    bn = (mind2[2].x == bv) ? (unsigned)(tid + 4 * 512) : bn;
    bn = (mind2[1].y == bv) ? (unsigned)(tid + 3 * 512) : bn;
    bn = (mind2[1].x == bv) ? (unsigned)(tid + 2 * 512) : bn;
    bn = (mind2[0].y == bv) ? (unsigned)(tid + 1 * 512) : bn;
    bn = (mind2[0].x == bv) ? (unsigned)tid : bn;

    const unsigned vb = __float_as_uint(bv);  // nonneg floats: monotone bits
    const unsigned wb = wave_umax(vb);        // wave max value
    unsigned tk = (vb == wb) ? ~bn : 0u;
    tk = wave_umax(tk);                       // ties -> smallest n
    const int par = t & 1;
    if (lane == 0) skey[par][wv] = ((unsigned long long)wb << 32) | tk;
    __syncthreads();
    const unsigned long long k0 = skey[par][0];
    const unsigned long long k1 = skey[par][1];
    const unsigned long long k2 = skey[par][2];
    const unsigned long long k3 = skey[par][3];
    const unsigned long long k4 = skey[par][4];
    const unsigned long long k5 = skey[par][5];
    const unsigned long long k6 = skey[par][6];
    const unsigned long long k7 = skey[par][7];
    const unsigned long long bb =
        umax64(umax64(umax64(k0, k1), umax64(k2, k3)),
               umax64(umax64(k4, k5), umax64(k6, k7)));
    const unsigned n = ~(unsigned)bb;
    const f32x4 qv = *(const f32x4*)(&sp[n][0]);  // one dependent b128 read
    qx = qv[0];
    qy = qv[1];
    qz = qv[2];
    if (tid == 0) sidx[t] = (int)n;  // LDS only
  }
  __syncthreads();
  // epilogue: bulk, coalesced global writes (once per kernel, off the chain)
  for (int i = tid; i < M; i += 512) {
    const int n = sidx[i];
    idx_out[b * M + i] = n;
    const f32x4 v = *(const f32x4*)(&sp[n][0]);
    pout[(size_t)(b * M + i) * 3 + 0] = v[0];
    pout[(size_t)(b * M + i) * 3 + 1] = v[1];
    pout[(size_t)(b * M + i) * 3 + 2] = v[2];
  }
}

// ---------------------------------------------------------------------------
// KNN v6 (round-15 version, prep removed): 512 threads = 8 waves = 8
// same-cloud centroids/block; pos4 staged once into LDS; per-round DPP
// argmin + winner-group rescan. Writes nbr.
// ---------------------------------------------------------------------------
__global__ __launch_bounds__(512) void knn6_kernel(const float* __restrict__ pos4,
                                                   const int* __restrict__ idx,
                                                   int* __restrict__ nbr) {
#pragma clang fp contract(off)
  __shared__ float sp4[N * 4];  // 64 KB
  const int tid  = threadIdx.x;
  const int wv   = tid >> 6;
  const int lane = tid & 63;
  const int cent = blockIdx.x * 8 + wv;   // 8 cents share one cloud
  const int b = cent >> 10;
  const float* p4 = pos4 + (size_t)b * N * 4;
  for (int i = tid; i < N; i += 512) {
    *(f32x4*)(sp4 + 4 * i) = *(const f32x4*)(p4 + 4 * i);
  }
  __syncthreads();

  const int sel = idx[cent];
  const f32x4 q = *(const f32x4*)(sp4 + 4 * sel);
  const f32x2 nqx = {-q[0], -q[0]};
  const f32x2 nqy = {-q[1], -q[1]};
  const f32x2 nqz = {-q[2], -q[2]};

  float d[64];
#pragma unroll
  for (int jj = 0; jj < 32; jj++) {
    const f32x4 v0 = *(const f32x4*)(sp4 + 4 * ((2 * jj + 0) * 64 + lane));
    const f32x4 v1 = *(const f32x4*)(sp4 + 4 * ((2 * jj + 1) * 64 + lane));
    f32x2 vx = {v0[0], v1[0]};
    f32x2 vy = {v0[1], v1[1]};
    f32x2 vz = {v0[2], v1[2]};
    f32x2 dx = vx + nqx;
    f32x2 dy = vy + nqy;
    f32x2 dz = vz + nqz;
    f32x2 s = (dx * dx + dy * dy) + dz * dz;  // numpy order, exact
    d[2 * jj + 0] = s.x;
    d[2 * jj + 1] = s.y;
  }
  float gv[8];
  int gj[8];
#pragma unroll
  for (int g = 0; g < 8; g++) {
    gv[g] = __builtin_inff();
    gj[g] = 8 * g;
#pragma unroll
    for (int e = 0; e < 8; e++) {
      const int j = 8 * g + e;
      bool c = d[j] < gv[g];  // strict: ascending j keeps smallest on ties
      gv[g] = c ? d[j] : gv[g];
      gj[g] = c ? j : gj[g];
    }
  }

  int* out = nbr + (size_t)cent * K;
  for (int r = 0; r < K; r++) {
    float bv = __builtin_inff();
    int bj = 0;
#pragma unroll
    for (int g = 0; g < 8; g++) {
      bool c = gv[g] < bv;
      bv = c ? gv[g] : bv;
      bj = c ? gj[g] : bj;
    }
    const unsigned bn = (unsigned)(bj * 64 + lane);
    const unsigned nb = ~__float_as_uint(bv);  // ~bits: umax -> min distance
    const unsigned wnb = wave_umax(nb);
    unsigned tk = (nb == wnb) ? (0xFFFFFFFFu - bn) : 0u;
    tk = wave_umax(tk);                        // ties -> smallest global n
    const unsigned wn = 0xFFFFFFFFu - tk;      // uniform across wave
    if (lane == 0) out[r] = (int)wn;

    const int wj = (int)(wn >> 6);
    const int wl = (int)(wn & 63);
    const int wg = wj >> 3;
#pragma unroll
    for (int g = 0; g < 8; g++) {
      if (g == wg) {  // scalar-uniform: only winner's group pays
#pragma unroll
        for (int e = 0; e < 8; e++) {
          if (8 * g + e == wj) {
            if (lane == wl) d[8 * g + e] = __builtin_inff();
          }
        }
        float nv = __builtin_inff();
        int nj = 8 * g;
#pragma unroll
        for (int e = 0; e < 8; e++) {
          const int j = 8 * g + e;
          bool c = d[j] < nv;
          nv = c ? d[j] : nv;
          nj = c ? j : nj;
        }
        gv[g] = nv;
        gj[g] = nj;
      }
    }
  }
}

// ---------------------------------------------------------------------------
// MLP v4 (round-15 version): wave-per-centroid, zero barriers, 256 thr =
// 4 waves = 4 cents, 34.8KB LDS -> 4 blocks/CU. Swapped layer-1 MFMA ->
// packed b64 A2 writes; rcp-based mish.
// ---------------------------------------------------------------------------
__global__ __launch_bounds__(256) void mlp4_kernel(
    const float* __restrict__ x, const float* __restrict__ pos4,
    const unsigned short* __restrict__ W1t, const unsigned short* __restrict__ W2t,
    const float* __restrict__ b1, const float* __restrict__ b2,
    const float* __restrict__ Wlin, const float* __restrict__ blin,
    const int* __restrict__ idx, const int* __restrict__ nbr,
    float* __restrict__ xout) {
  __shared__ unsigned short sA2[4][32][LDH];
  const int tid  = threadIdx.x;
  const int wv   = tid >> 6;
  const int lane = tid & 63;
  const int lrow = lane & 15;
  const int g    = lane >> 4;
  unsigned short* A2 = &sA2[wv][0][0];
  const int cent = blockIdx.x * 4 + wv;
  const int b    = cent >> 10;
  const int sel  = idx[cent];
  const float* p4 = pos4 + (size_t)b * N * 4;
  const f32x4 q = *(const f32x4*)(p4 + 4 * sel);
  const float qx = q[0], qy = q[1], qz = q[2];

  const int n0 = nbr[(size_t)cent * K + lrow];
  const int n1 = nbr[(size_t)cent * K + 16 + lrow];

  short8 a0[3], a1[3];
  {
    const float* xr0 = x + ((size_t)b * N + n0) * CIN;
    const float* xr1 = x + ((size_t)b * N + n1) * CIN;
#pragma unroll
    for (int kc = 0; kc < 2; kc++) {
      const int k0 = kc * 32 + g * 8;
      f32x4 u0 = *(const f32x4*)(xr0 + k0);
      f32x4 u1 = *(const f32x4*)(xr0 + k0 + 4);
      f32x4 v0 = *(const f32x4*)(xr1 + k0);
      f32x4 v1 = *(const f32x4*)(xr1 + k0 + 4);
      short8 ha, hb;
#pragma unroll
      for (int e = 0; e < 4; e++) {
        ha[e] = (short)f2bf(u0[e]);
        ha[e + 4] = (short)f2bf(u1[e]);
        hb[e] = (short)f2bf(v0[e]);
        hb[e + 4] = (short)f2bf(v1[e]);
      }
      a0[kc] = ha;
      a1[kc] = hb;
    }
    short8 z = {};
    a0[2] = z;
    a1[2] = z;
    if (g == 0) {  // k = 64..71: {rel.x, rel.y, rel.z, 0...}
      float r0x = p4[4 * n0 + 0] - qx, r0y = p4[4 * n0 + 1] - qy, r0z = p4[4 * n0 + 2] - qz;
      float r1x = p4[4 * n1 + 0] - qx, r1y = p4[4 * n1 + 1] - qy, r1z = p4[4 * n1 + 2] - qz;
      a0[2][0] = (short)f2bf(r0x); a0[2][1] = (short)f2bf(r0y); a0[2][2] = (short)f2bf(r0z);
      a1[2][0] = (short)f2bf(r1x); a1[2][1] = (short)f2bf(r1y); a1[2][2] = (short)f2bf(r1z);
    }
  }

  // layer 1 (swapped): lane holds 4 k-consecutive channels -> packed b64
#pragma unroll 2
  for (int nt = 0; nt < 8; nt++) {
    const unsigned short* w1r = W1t + (size_t)(nt * 16 + lrow) * K1 + g * 8;
    f32x4 c0 = {}, c1 = {};
#pragma unroll
    for (int kc = 0; kc < 3; kc++) {
      short8 afr = *(const short8*)(w1r + kc * 32);
      c0 = __builtin_amdgcn_mfma_f32_16x16x32_bf16(afr, a0[kc], c0, 0, 0, 0);
      c1 = __builtin_amdgcn_mfma_f32_16x16x32_bf16(afr, a1[kc], c1, 0, 0, 0);
    }
    const int kbase = nt * 16 + g * 4;
    const f32x4 bb = *(const f32x4*)(b1 + kbase);
    short4v h0, h1;
#pragma unroll
    for (int reg = 0; reg < 4; reg++) {
      h0[reg] = (short)f2bf(fast_mish(c0[reg] + bb[reg]));
      h1[reg] = (short)f2bf(fast_mish(c1[reg] + bb[reg]));
    }
    *(short4v*)(A2 + lrow * LDH + kbase) = h0;
    *(short4v*)(A2 + (16 + lrow) * LDH + kbase) = h1;
  }

  f32x4 xq[4];
  {
    const float* xs = x + ((size_t)b * N + sel) * CIN + g * 16;
#pragma unroll
    for (int v = 0; v < 4; v++) xq[v] = *(const f32x4*)(xs + 4 * v);
  }

#pragma unroll 2
  for (int nt = 0; nt < 8; nt++) {
    const unsigned short* w2r = W2t + (size_t)(nt * 16 + lrow) * 128 + g * 8;
    f32x4 c0 = {}, c1 = {};
#pragma unroll
    for (int kc = 0; kc < 4; kc++) {
      short8 af0 = *(const short8*)(A2 + lrow * LDH + kc * 32 + g * 8);
      short8 af1 = *(const short8*)(A2 + (16 + lrow) * LDH + kc * 32 + g * 8);
      short8 bfr = *(const short8*)(w2r + kc * 32);
      c0 = __builtin_amdgcn_mfma_f32_16x16x32_bf16(af0, bfr, c0, 0, 0, 0);
      c1 = __builtin_amdgcn_mfma_f32_16x16x32_bf16(af1, bfr, c1, 0, 0, 0);
    }
    float pm = fmaxf(fmaxf(fmaxf(c0[0], c0[1]), fmaxf(c0[2], c0[3])),
                     fmaxf(fmaxf(c1[0], c1[1]), fmaxf(c1[2], c1[3])));
    pm = fmaxf(pm, __shfl_xor(pm, 16, 64));
    pm = fmaxf(pm, __shfl_xor(pm, 32, 64));  // max over all 32 rows, col j
    const int j = nt * 16 + lrow;
    float s = 0.f;
#pragma unroll
    for (int e = 0; e < 16; e++) {
      s += xq[e >> 2][e & 3] * Wlin[(g * 16 + e) * 128 + j];
    }
    s += __shfl_xor(s, 16, 64);
    s += __shfl_xor(s, 32, 64);  // full 64-k dot
    if (g == 0) {
      xout[(size_t)cent * 128 + j] = pm + b2[j] + s + blin[j];
    }
  }
}

// ---------------------------------------------------------------------------
extern "C" void kernel_launch(void* const* d_in, const int* in_sizes, int n_in,
                              void* d_out, int out_size, void* d_ws, size_t ws_size,
                              hipStream_t stream) {
  const float* x    = (const float*)d_in[0];
  const float* pos  = (const float*)d_in[1];
  const float* W1   = (const float*)d_in[2];
  const float* b1   = (const float*)d_in[3];
  const float* W2   = (const float*)d_in[4];
  const float* b2   = (const float*)d_in[5];
  const float* Wlin = (const float*)d_in[6];
  const float* blin = (const float*)d_in[7];

  float* out  = (float*)d_out;                 // float32 outputs
  float* xout = out;                           // [B*M*COUT]
  float* pout = out + (size_t)B * M * COUT;    // [B*M*3]

  char* ws = (char*)d_ws;
  int* idx            = (int*)ws;                           // 64 KB
  int* nbr            = (int*)(ws + 65536);                 // 2 MB
  unsigned short* W1t = (unsigned short*)(ws + 65536 + 2097152);          // 24 KB
  unsigned short* W2t = (unsigned short*)(ws + 65536 + 2097152 + 24576);  // 32 KB
  float* pos4         = (float*)(ws + 65536 + 2097152 + 24576 + 32768);   // 1 MB

  fps11_kernel<<<dim3(B + 128), dim3(512), 0, stream>>>(pos, idx, pout, pos4,
                                                        W1, W2, W1t, W2t);
  knn6_kernel<<<dim3(B * M / 8), dim3(512), 0, stream>>>(pos4, idx, nbr);
  mlp4_kernel<<<dim3(B * M / 4), dim3(256), 0, stream>>>(
      x, pos4, W1t, W2t, b1, b2, Wlin, blin, idx, nbr, xout);
}